// Round 3
// baseline (464.448 us; speedup 1.0000x reference)
//
#include <hip/hip_runtime.h>
#include <stdint.h>
#include <stddef.h>

// AttnBlock: x[32,32,32,512] fp32 -> groupnorm(32) -> q/k/v 1x1 conv -> attn(seq=1024) -> proj -> +x
// bf16 MFMA GEMMs (m93/m97 structure), fp32 stats/accum/epilogues.
// R3: LDS-transpose packed epilogue (kills TCC write-allocate fetches from 2B scatter stores).

typedef short bh8 __attribute__((ext_vector_type(8)));   // 8 bf16 payload (4 VGPRs)
typedef __bf16 bf8 __attribute__((ext_vector_type(8)));  // builtin operand type
typedef float f4 __attribute__((ext_vector_type(4)));
typedef unsigned short u16;

#define NB 32
#define HW 1024
#define NC 512
#define NM (NB * HW)   // 32768 rows total

__device__ __forceinline__ u16 f2bf(float f) {
    union { float f; uint32_t u; } v; v.f = f;
    uint32_t r = v.u + 0x7FFFu + ((v.u >> 16) & 1u);  // RNE
    return (u16)(r >> 16);
}
__device__ __forceinline__ float bf2f(u16 h) {
    union { uint32_t u; float f; } v; v.u = ((uint32_t)h) << 16;
    return v.f;
}

using gas_p = const __attribute__((address_space(1))) void*;
using las_p = __attribute__((address_space(3))) void*;

__device__ __forceinline__ void async16(const void* g, void* l) {
    __builtin_amdgcn_global_load_lds((gas_p)g, (las_p)l, 16, 0, 0);
}

__device__ __forceinline__ f4 mfma16(bh8 a, bh8 b, f4 c) {
    return __builtin_amdgcn_mfma_f32_16x16x32_bf16(
        __builtin_bit_cast(bf8, a), __builtin_bit_cast(bf8, b), c, 0, 0, 0);
}

// ---------------------------------------------------------------- transpose weights
__global__ __launch_bounds__(256) void transpose_weights(
    const float* __restrict__ wq, const float* __restrict__ wk,
    const float* __restrict__ wv, const float* __restrict__ wp,
    u16* __restrict__ wT)
{
    int idx = blockIdx.x * 256 + threadIdx.x;      // 0 .. 4*512*512-1
    int m = idx >> 18;
    int r = idx & 0x3FFFF;                          // r = k*512 + n (coalesced read)
    int k = r >> 9, n = r & 511;
    const float* w = (m == 0) ? wq : (m == 1) ? wk : (m == 2) ? wv : wp;
    wT[((size_t)m << 18) + (size_t)n * 512 + k] = f2bf(w[r]);
}

// ---------------------------------------------------------------- group norm (3 stages)
__global__ __launch_bounds__(256) void gn_partial(
    const float* __restrict__ x, float2* __restrict__ part)
{
    const int b = blockIdx.x >> 3, s = blockIdx.x & 7;
    const int t = threadIdx.x;
    const int c0 = (t & 127) * 4;
    const int pr = t >> 7;
    const float* xb = x + (size_t)b * HW * NC + (size_t)(s * 128) * NC + c0;
    float sum = 0.f, sq = 0.f;
#pragma unroll 8
    for (int i = 0; i < 64; ++i) {
        const float4 v = *(const float4*)(xb + (size_t)(pr + i * 2) * NC);
        sum += v.x + v.y + v.z + v.w;
        sq  += v.x * v.x + v.y * v.y + v.z * v.z + v.w * v.w;
    }
    __shared__ float2 red[256];
    red[t] = make_float2(sum, sq);
    __syncthreads();
    if (t < 32) {
        float S = 0.f, Q = 0.f;
#pragma unroll
        for (int p = 0; p < 2; ++p)
#pragma unroll
            for (int j = 0; j < 4; ++j) {
                const float2 v = red[t * 4 + j + p * 128];
                S += v.x; Q += v.y;
            }
        part[(size_t)blockIdx.x * 32 + t] = make_float2(S, Q);
    }
}

__global__ __launch_bounds__(256) void gn_stats(
    const float2* __restrict__ part, float2* __restrict__ stats)
{
    const int p = blockIdx.x * 256 + threadIdx.x;   // 0..1023
    const int b = p >> 5, g = p & 31;
    float S = 0.f, Q = 0.f;
#pragma unroll
    for (int s = 0; s < 8; ++s) {
        const float2 v = part[((size_t)(b * 8 + s)) * 32 + g];
        S += v.x; Q += v.y;
    }
    const float mean = S * (1.f / 16384.f);
    const float var = Q * (1.f / 16384.f) - mean * mean;
    stats[p] = make_float2(mean, rsqrtf(var + 1e-6f));
}

__global__ __launch_bounds__(256) void gn_apply(
    const float* __restrict__ x, const float2* __restrict__ stats,
    const float* __restrict__ scale, const float* __restrict__ bias,
    u16* __restrict__ hn)
{
    const size_t idx = (size_t)blockIdx.x * 256 + threadIdx.x;  // float4 index
    const size_t e = idx * 4;
    const int c0 = (int)(e & 511);
    const int bg = (int)(e >> 19) * 32 + (c0 >> 4);
    const float2 st = stats[bg];
    const float4 v = *(const float4*)(x + e);
    const float4 sc = *(const float4*)(scale + c0);
    const float4 bi = *(const float4*)(bias + c0);
    ushort4 o;
    o.x = f2bf((v.x - st.x) * st.y * sc.x + bi.x);
    o.y = f2bf((v.y - st.x) * st.y * sc.y + bi.y);
    o.z = f2bf((v.z - st.x) * st.y * sc.z + bi.z);
    o.w = f2bf((v.w - st.x) * st.y * sc.w + bi.w);
    *(ushort4*)(hn + e) = o;
}

// ---------------------------------------------------------------- GEMM (B^T form)
// C[M,N] = A[M,K] * Bt[N,K]^T, bf16 in, fp32 accum. 128x128 tile, BK=32,
// 256 threads = 4 waves (2x2), each wave 4x4 of 16x16x32 MFMA.
// MODE 0: bf16 C0 = alpha*acc (batched via blockIdx.z), packed LDS epilogue
// MODE 3: fp32 C0 = acc + b0[col] + resid[row*ldc+col] (full-line fp32 stores)
// MODE 4: fused QKV: n-seg 0/1 -> q/k (packed rows); seg 2 -> vT transposed packed
template <int MODE>
__global__ __launch_bounds__(256) void gemm_bt(
    const u16* __restrict__ A, const u16* __restrict__ Bt,
    void* __restrict__ C0, void* __restrict__ C1,
    const float* __restrict__ b0, const float* __restrict__ b1,
    const float* __restrict__ b2, const float* __restrict__ resid,
    int K, int ldc, long strA, long strB, long strC, float alpha)
{
    // 18 KB shared: K-loop tiles (2x8KB) alias the epilogue buffer.
    __shared__ __align__(16) u16 smem[9216];
    u16* tA = smem;          // [128*32]
    u16* tB = smem + 4096;   // [128*32]
    const int tid = threadIdx.x;
    const int w = tid >> 6, lane = tid & 63;
    const int z = blockIdx.z;
    const u16* Ab = A + (size_t)z * strA;
    const u16* Bb = Bt + (size_t)z * strB;
    const int m0 = blockIdx.y * 128;
    const int n0 = blockIdx.x * 128;
    const int wm = (w >> 1) * 64, wn = (w & 1) * 64;
    const int r = lane & 15, q4 = lane >> 4;

    f4 acc[4][4];
#pragma unroll
    for (int i = 0; i < 4; ++i)
#pragma unroll
        for (int j = 0; j < 4; ++j) {
            f4 zr = {0.f, 0.f, 0.f, 0.f};
            acc[i][j] = zr;
        }

    for (int k0 = 0; k0 < K; k0 += 32) {
#pragma unroll
        for (int issue = 0; issue < 2; ++issue) {
            const int cbase = issue * 256 + w * 64;     // wave-uniform
            const int chunk = cbase + lane;
            const int row = chunk >> 2, cc = chunk & 3;
            async16(Ab + (size_t)(m0 + row) * K + (k0 + cc * 8), &tA[(size_t)cbase * 8]);
            async16(Bb + (size_t)(n0 + row) * K + (k0 + cc * 8), &tB[(size_t)cbase * 8]);
        }
        __syncthreads();
        bh8 af[4], bfr[4];
#pragma unroll
        for (int t = 0; t < 4; ++t)
            af[t] = *(const bh8*)&tA[(wm + t * 16 + r) * 32 + q4 * 8];
#pragma unroll
        for (int t = 0; t < 4; ++t)
            bfr[t] = *(const bh8*)&tB[(wn + t * 16 + r) * 32 + q4 * 8];
#pragma unroll
        for (int mt = 0; mt < 4; ++mt)
#pragma unroll
            for (int nt = 0; nt < 4; ++nt)
                acc[mt][nt] = mfma16(af[mt], bfr[nt], acc[mt][nt]);
        __syncthreads();
    }

    // ---------------- epilogue. C/D layout: col = lane&15, row = (lane>>4)*4 + i
    if (MODE == 3) {
        // fp32 + bias + residual, direct (full-line coverage per quad-row)
#pragma unroll
        for (int mt = 0; mt < 4; ++mt)
#pragma unroll
            for (int nt = 0; nt < 4; ++nt) {
                const int col = n0 + wn + nt * 16 + r;
                const float bv = b0[col];
#pragma unroll
                for (int i = 0; i < 4; ++i) {
                    const size_t idx = (size_t)(m0 + wm + mt * 16 + q4 * 4 + i) * ldc + col;
                    ((float*)C0)[idx] = acc[mt][nt][i] + bv + resid[idx];
                }
            }
        return;
    }

    const int seg_blk = (MODE == 4) ? (n0 >> 9) : 0;     // wave-uniform per block
    if (MODE == 0 || seg_blk < 2) {
        // packed row-major path: ebuf[64][136] bf16 per half
        u16* Cd;
        int ld, cb;
        const float* bp_ = nullptr;
        if (MODE == 4) {
            Cd = (u16*)C0 + (size_t)seg_blk * (size_t)NM * 512;
            ld = 512; cb = n0 & 511;
            bp_ = (seg_blk == 0) ? b0 : b1;
        } else {
            Cd = (u16*)C0 + (size_t)z * strC;
            ld = ldc; cb = n0;
        }
#pragma unroll
        for (int p = 0; p < 2; ++p) {
            __syncthreads();
            if ((w >> 1) == p) {
#pragma unroll
                for (int mt = 0; mt < 4; ++mt)
#pragma unroll
                    for (int nt = 0; nt < 4; ++nt) {
                        const int col = wn + nt * 16 + r;
                        const float bv = (MODE == 4) ? bp_[cb + col] : 0.f;
#pragma unroll
                        for (int i = 0; i < 4; ++i) {
                            const int rl = mt * 16 + q4 * 4 + i;
                            float v = acc[mt][nt][i];
                            v = (MODE == 0) ? v * alpha : v + bv;
                            smem[rl * 136 + col] = f2bf(v);
                        }
                    }
            }
            __syncthreads();
#pragma unroll
            for (int j = 0; j < 4; ++j) {
                const int idx = j * 256 + tid;          // 1024 chunks of 8 u16
                const int rr = idx >> 4, cc = (idx & 15) << 3;
                const bh8 val = *(const bh8*)&smem[rr * 136 + cc];
                *(bh8*)&Cd[(size_t)(m0 + p * 64 + rr) * ld + cb + cc] = val;
            }
        }
    } else {
        // vT transposed packed path: ebuf[128][72] (col-major) per half
        const int cb = n0 & 511;
        const int bbi = m0 >> 10;
#pragma unroll
        for (int p = 0; p < 2; ++p) {
            __syncthreads();
            if ((w >> 1) == p) {
#pragma unroll
                for (int mt = 0; mt < 4; ++mt)
#pragma unroll
                    for (int nt = 0; nt < 4; ++nt) {
                        const int col = wn + nt * 16 + r;
                        const float bv = b2[cb + col];
#pragma unroll
                        for (int i = 0; i < 4; ++i) {
                            const int rl = mt * 16 + q4 * 4 + i;
                            smem[col * 72 + rl] = f2bf(acc[mt][nt][i] + bv);
                        }
                    }
            }
            __syncthreads();
            const int ml0 = (m0 & 1023) + p * 64;
#pragma unroll
            for (int j = 0; j < 4; ++j) {
                const int idx = j * 256 + tid;          // 1024 chunks of 8 u16
                const int col = idx >> 3, rseg = (idx & 7) << 3;
                const bh8 val = *(const bh8*)&smem[col * 72 + rseg];
                *(bh8*)&((u16*)C1)[((size_t)(bbi * 512) + cb + col) * 1024 + ml0 + rseg] = val;
            }
        }
    }
}

// ---------------------------------------------------------------- softmax (in place)
__global__ __launch_bounds__(256) void softmax_kernel(u16* __restrict__ s)
{
    const int wave = (blockIdx.x << 2) | (threadIdx.x >> 6);
    const int lane = threadIdx.x & 63;
    u16* rowp = s + (size_t)wave * 1024;

    float v[16];
#pragma unroll
    for (int c = 0; c < 4; ++c) {
        const ushort4 raw = *(const ushort4*)(rowp + c * 256 + lane * 4);
        v[c * 4 + 0] = bf2f(raw.x);
        v[c * 4 + 1] = bf2f(raw.y);
        v[c * 4 + 2] = bf2f(raw.z);
        v[c * 4 + 3] = bf2f(raw.w);
    }
    float m = -1e30f;
#pragma unroll
    for (int i = 0; i < 16; ++i) m = fmaxf(m, v[i]);
#pragma unroll
    for (int off = 32; off; off >>= 1) m = fmaxf(m, __shfl_xor(m, off));
    float sum = 0.f;
#pragma unroll
    for (int i = 0; i < 16; ++i) {
        v[i] = __expf(v[i] - m);
        sum += v[i];
    }
#pragma unroll
    for (int off = 32; off; off >>= 1) sum += __shfl_xor(sum, off);
    const float inv = 1.0f / sum;
#pragma unroll
    for (int c = 0; c < 4; ++c) {
        ushort4 o;
        o.x = f2bf(v[c * 4 + 0] * inv);
        o.y = f2bf(v[c * 4 + 1] * inv);
        o.z = f2bf(v[c * 4 + 2] * inv);
        o.w = f2bf(v[c * 4 + 3] * inv);
        *(ushort4*)(rowp + c * 256 + lane * 4) = o;
    }
}

// ---------------------------------------------------------------- launch
extern "C" void kernel_launch(void* const* d_in, const int* in_sizes, int n_in,
                              void* d_out, int out_size, void* d_ws, size_t ws_size,
                              hipStream_t stream)
{
    (void)in_sizes; (void)n_in; (void)out_size; (void)ws_size;
    const float* x   = (const float*)d_in[0];
    const float* nsc = (const float*)d_in[1];
    const float* nbi = (const float*)d_in[2];
    const float* wq  = (const float*)d_in[3];
    const float* bq  = (const float*)d_in[4];
    const float* wk  = (const float*)d_in[5];
    const float* bk  = (const float*)d_in[6];
    const float* wv  = (const float*)d_in[7];
    const float* bv  = (const float*)d_in[8];
    const float* wp  = (const float*)d_in[9];
    const float* bp  = (const float*)d_in[10];
    float* out = (float*)d_out;

    char* ws = (char*)d_ws;
    u16* qb = (u16*)(ws);                        // 32 MB  [32768,512]  (q)
    u16* kb = (u16*)(ws + (32ull << 20));        // 32 MB  [32768,512]  (k)
    u16* vT = (u16*)(ws + (64ull << 20));        // 32 MB  [32,512,1024]
    u16* sb = (u16*)(ws + (96ull << 20));        // 64 MB  [32,1024,1024] (scores)
    u16* hn = (u16*)(ws + (160ull << 20));       // 32 MB  [32768,512]
    u16* ao = hn;                                 // reuse: hn dead after QKV
    u16* wT = (u16*)(ws + (192ull << 20));       // 2 MB   [4*512,512] stacked q,k,v,p
    float2* gnp = (float2*)sb;                   // 64 KB partials (dead before scores)
    float2* gns = (float2*)(ws + (97ull << 20)); // 8 KB stats

    transpose_weights<<<4096, 256, 0, stream>>>(wq, wk, wv, wp, wT);
    gn_partial<<<256, 256, 0, stream>>>(x, gnp);
    gn_stats<<<4, 256, 0, stream>>>(gnp, gns);
    gn_apply<<<16384, 256, 0, stream>>>(x, gns, nsc, nbi, hn);

    const dim3 blk(256);
    const dim3 gqkv(12, 256, 1);                 // fused QKV: N=1536, M=32768
    gemm_bt<4><<<gqkv, blk, 0, stream>>>(hn, wT, qb, vT, bq, bk, bv, nullptr,
                                         512, 512, 0, 0, 0, 1.f);

    const dim3 g2(8, 8, 32);                     // scores: N=1024, M=1024, 32 batches
    gemm_bt<0><<<g2, blk, 0, stream>>>(qb, kb, sb, nullptr, nullptr, nullptr, nullptr, nullptr,
                                       512, 1024, 1024L * 512, 1024L * 512, 1024L * 1024,
                                       0.04419417382415922f);  // 512^-0.5
    softmax_kernel<<<8192, blk, 0, stream>>>(sb);

    const dim3 g3(4, 8, 32);                     // out: N=512, M=1024, 32 batches
    gemm_bt<0><<<g3, blk, 0, stream>>>(sb, vT, ao, nullptr, nullptr, nullptr, nullptr, nullptr,
                                       1024, 512, 1024L * 1024, 512L * 1024, 1024L * 512,
                                       1.f);

    const dim3 g1(4, 256, 1);                    // proj: N=512, M=32768
    gemm_bt<3><<<g1, blk, 0, stream>>>(ao, wT + 3 * 262144, out, nullptr, bp, nullptr, nullptr, x,
                                       512, 512, 0, 0, 0, 1.f);
}

// Round 5
// 428.176 us; speedup vs baseline: 1.0847x; 1.0847x over previous
//
#include <hip/hip_runtime.h>
#include <stdint.h>
#include <stddef.h>

// AttnBlock: x[32,32,32,512] fp32 -> groupnorm(32) -> q/k/v 1x1 conv -> attn(seq=1024) -> proj -> +x
// bf16 MFMA GEMMs (m93/m97 structure), fp32 stats/accum/epilogues.
// R5: fix R4's QKV swizzle grid (12 n-blocks, not 6 -> 3072 blocks, SWZ=12).
// XCD-aware swizzle: all n-blocks of an m-strip run consecutively on one XCD.

typedef short bh8 __attribute__((ext_vector_type(8)));   // 8 bf16 payload (4 VGPRs)
typedef __bf16 bf8 __attribute__((ext_vector_type(8)));  // builtin operand type
typedef float f4 __attribute__((ext_vector_type(4)));
typedef unsigned short u16;

#define NB 32
#define HW 1024
#define NC 512
#define NM (NB * HW)   // 32768 rows total

__device__ __forceinline__ u16 f2bf(float f) {
    union { float f; uint32_t u; } v; v.f = f;
    uint32_t r = v.u + 0x7FFFu + ((v.u >> 16) & 1u);  // RNE
    return (u16)(r >> 16);
}
__device__ __forceinline__ float bf2f(u16 h) {
    union { uint32_t u; float f; } v; v.u = ((uint32_t)h) << 16;
    return v.f;
}

using gas_p = const __attribute__((address_space(1))) void*;
using las_p = __attribute__((address_space(3))) void*;

__device__ __forceinline__ void async16(const void* g, void* l) {
    __builtin_amdgcn_global_load_lds((gas_p)g, (las_p)l, 16, 0, 0);
}

__device__ __forceinline__ f4 mfma16(bh8 a, bh8 b, f4 c) {
    return __builtin_amdgcn_mfma_f32_16x16x32_bf16(
        __builtin_bit_cast(bf8, a), __builtin_bit_cast(bf8, b), c, 0, 0, 0);
}

// ---------------------------------------------------------------- transpose weights
__global__ __launch_bounds__(256) void transpose_weights(
    const float* __restrict__ wq, const float* __restrict__ wk,
    const float* __restrict__ wv, const float* __restrict__ wp,
    u16* __restrict__ wT)
{
    int idx = blockIdx.x * 256 + threadIdx.x;      // 0 .. 4*512*512-1
    int m = idx >> 18;
    int r = idx & 0x3FFFF;                          // r = k*512 + n (coalesced read)
    int k = r >> 9, n = r & 511;
    const float* w = (m == 0) ? wq : (m == 1) ? wk : (m == 2) ? wv : wp;
    wT[((size_t)m << 18) + (size_t)n * 512 + k] = f2bf(w[r]);
}

// ---------------------------------------------------------------- group norm (3 stages)
__global__ __launch_bounds__(256) void gn_partial(
    const float* __restrict__ x, float2* __restrict__ part)
{
    const int b = blockIdx.x >> 3, s = blockIdx.x & 7;
    const int t = threadIdx.x;
    const int c0 = (t & 127) * 4;
    const int pr = t >> 7;
    const float* xb = x + (size_t)b * HW * NC + (size_t)(s * 128) * NC + c0;
    float sum = 0.f, sq = 0.f;
#pragma unroll 8
    for (int i = 0; i < 64; ++i) {
        const float4 v = *(const float4*)(xb + (size_t)(pr + i * 2) * NC);
        sum += v.x + v.y + v.z + v.w;
        sq  += v.x * v.x + v.y * v.y + v.z * v.z + v.w * v.w;
    }
    __shared__ float2 red[256];
    red[t] = make_float2(sum, sq);
    __syncthreads();
    if (t < 32) {
        float S = 0.f, Q = 0.f;
#pragma unroll
        for (int p = 0; p < 2; ++p)
#pragma unroll
            for (int j = 0; j < 4; ++j) {
                const float2 v = red[t * 4 + j + p * 128];
                S += v.x; Q += v.y;
            }
        part[(size_t)blockIdx.x * 32 + t] = make_float2(S, Q);
    }
}

__global__ __launch_bounds__(256) void gn_stats(
    const float2* __restrict__ part, float2* __restrict__ stats)
{
    const int p = blockIdx.x * 256 + threadIdx.x;   // 0..1023
    const int b = p >> 5, g = p & 31;
    float S = 0.f, Q = 0.f;
#pragma unroll
    for (int s = 0; s < 8; ++s) {
        const float2 v = part[((size_t)(b * 8 + s)) * 32 + g];
        S += v.x; Q += v.y;
    }
    const float mean = S * (1.f / 16384.f);
    const float var = Q * (1.f / 16384.f) - mean * mean;
    stats[p] = make_float2(mean, rsqrtf(var + 1e-6f));
}

__global__ __launch_bounds__(256) void gn_apply(
    const float* __restrict__ x, const float2* __restrict__ stats,
    const float* __restrict__ scale, const float* __restrict__ bias,
    u16* __restrict__ hn)
{
    const size_t idx = (size_t)blockIdx.x * 256 + threadIdx.x;  // float4 index
    const size_t e = idx * 4;
    const int c0 = (int)(e & 511);
    const int bg = (int)(e >> 19) * 32 + (c0 >> 4);
    const float2 st = stats[bg];
    const float4 v = *(const float4*)(x + e);
    const float4 sc = *(const float4*)(scale + c0);
    const float4 bi = *(const float4*)(bias + c0);
    ushort4 o;
    o.x = f2bf((v.x - st.x) * st.y * sc.x + bi.x);
    o.y = f2bf((v.y - st.x) * st.y * sc.y + bi.y);
    o.z = f2bf((v.z - st.x) * st.y * sc.z + bi.z);
    o.w = f2bf((v.w - st.x) * st.y * sc.w + bi.w);
    *(ushort4*)(hn + e) = o;
}

// ---------------------------------------------------------------- GEMM (B^T form)
// C[M,N] = A[M,K] * Bt[N,K]^T, bf16 in, fp32 accum. 128x128 tile, BK=32,
// 256 threads = 4 waves (2x2), each wave 4x4 of 16x16x32 MFMA.
// MODE 0: bf16 C0 = alpha*acc (batched via blockIdx.z)
// MODE 3: fp32 C0 = acc + b0[col] + resid[row*ldc+col]
// MODE 4: fused QKV: col<1024 -> q/k (seg-strided); col>=1024 -> vT transposed
// SWZ > 0: 1D grid of (8 XCDs x mper x SWZ) blocks; xcd = bid&7, s = bid>>3,
//          m-strip = xcd*mper + s/SWZ, n-block = s%SWZ. Grid MUST equal
//          8 * mper * SWZ with SWZ == number of n-blocks.
template <int MODE, int SWZ>
__global__ __launch_bounds__(256) void gemm_bt(
    const u16* __restrict__ A, const u16* __restrict__ Bt,
    void* __restrict__ C0, void* __restrict__ C1,
    const float* __restrict__ b0, const float* __restrict__ b1,
    const float* __restrict__ b2, const float* __restrict__ resid,
    int K, int ldc, long strA, long strB, long strC, float alpha)
{
    __shared__ __align__(16) u16 tA[128 * 32];
    __shared__ __align__(16) u16 tB[128 * 32];
    const int tid = threadIdx.x;
    const int w = tid >> 6, lane = tid & 63;
    const int z = blockIdx.z;
    const u16* Ab = A + (size_t)z * strA;
    const u16* Bb = Bt + (size_t)z * strB;
    int m0, n0;
    if (SWZ > 0) {
        const int g = blockIdx.x;
        const int xcd = g & 7, s = g >> 3;
        const int mper = (int)(gridDim.x >> 3) / SWZ;
        m0 = (xcd * mper + s / SWZ) * 128;
        n0 = (s % SWZ) * 128;
    } else {
        m0 = blockIdx.y * 128;
        n0 = blockIdx.x * 128;
    }
    const int wm = (w >> 1) * 64, wn = (w & 1) * 64;
    const int r = lane & 15, q4 = lane >> 4;

    f4 acc[4][4];
#pragma unroll
    for (int i = 0; i < 4; ++i)
#pragma unroll
        for (int j = 0; j < 4; ++j) {
            f4 zr = {0.f, 0.f, 0.f, 0.f};
            acc[i][j] = zr;
        }

    for (int k0 = 0; k0 < K; k0 += 32) {
#pragma unroll
        for (int issue = 0; issue < 2; ++issue) {
            const int cbase = issue * 256 + w * 64;     // wave-uniform
            const int chunk = cbase + lane;
            const int row = chunk >> 2, cc = chunk & 3;
            async16(Ab + (size_t)(m0 + row) * K + (k0 + cc * 8), &tA[(size_t)cbase * 8]);
            async16(Bb + (size_t)(n0 + row) * K + (k0 + cc * 8), &tB[(size_t)cbase * 8]);
        }
        __syncthreads();
        bh8 af[4], bfr[4];
#pragma unroll
        for (int t = 0; t < 4; ++t)
            af[t] = *(const bh8*)&tA[(wm + t * 16 + r) * 32 + q4 * 8];
#pragma unroll
        for (int t = 0; t < 4; ++t)
            bfr[t] = *(const bh8*)&tB[(wn + t * 16 + r) * 32 + q4 * 8];
#pragma unroll
        for (int mt = 0; mt < 4; ++mt)
#pragma unroll
            for (int nt = 0; nt < 4; ++nt)
                acc[mt][nt] = mfma16(af[mt], bfr[nt], acc[mt][nt]);
        __syncthreads();
    }

    // epilogue: C/D layout col = lane&15, row = (lane>>4)*4 + i
#pragma unroll
    for (int mt = 0; mt < 4; ++mt) {
#pragma unroll
        for (int nt = 0; nt < 4; ++nt) {
            const int col = n0 + wn + nt * 16 + r;
            const int row0 = m0 + wm + mt * 16 + q4 * 4;
            if (MODE == 0) {
#pragma unroll
                for (int i = 0; i < 4; ++i)
                    ((u16*)C0)[(size_t)z * strC + (size_t)(row0 + i) * ldc + col] =
                        f2bf(acc[mt][nt][i] * alpha);
            } else if (MODE == 3) {
                const float bv = b0[col];
#pragma unroll
                for (int i = 0; i < 4; ++i) {
                    const size_t idx = (size_t)(row0 + i) * ldc + col;
                    ((float*)C0)[idx] = acc[mt][nt][i] + bv + resid[idx];
                }
            } else {  // MODE 4: fused QKV
                const int seg = col >> 9, cl = col & 511;
                const float bv = (seg == 0 ? b0 : seg == 1 ? b1 : b2)[cl];
                if (seg < 2) {
                    u16* base = (u16*)C0 + (size_t)seg * (size_t)NM * 512;
#pragma unroll
                    for (int i = 0; i < 4; ++i)
                        base[(size_t)(row0 + i) * 512 + cl] = f2bf(acc[mt][nt][i] + bv);
                } else {
                    const int bb = row0 >> 10, ml = row0 & 1023;
                    ushort4 o;
                    o.x = f2bf(acc[mt][nt][0] + bv);
                    o.y = f2bf(acc[mt][nt][1] + bv);
                    o.z = f2bf(acc[mt][nt][2] + bv);
                    o.w = f2bf(acc[mt][nt][3] + bv);
                    *(ushort4*)((u16*)C1 + ((size_t)(bb * 512 + cl)) * 1024 + ml) = o;
                }
            }
        }
    }
}

// ---------------------------------------------------------------- softmax (in place)
__global__ __launch_bounds__(256) void softmax_kernel(u16* __restrict__ s)
{
    const int wave = (blockIdx.x << 2) | (threadIdx.x >> 6);
    const int lane = threadIdx.x & 63;
    u16* rowp = s + (size_t)wave * 1024;

    float v[16];
#pragma unroll
    for (int c = 0; c < 4; ++c) {
        const ushort4 raw = *(const ushort4*)(rowp + c * 256 + lane * 4);
        v[c * 4 + 0] = bf2f(raw.x);
        v[c * 4 + 1] = bf2f(raw.y);
        v[c * 4 + 2] = bf2f(raw.z);
        v[c * 4 + 3] = bf2f(raw.w);
    }
    float m = -1e30f;
#pragma unroll
    for (int i = 0; i < 16; ++i) m = fmaxf(m, v[i]);
#pragma unroll
    for (int off = 32; off; off >>= 1) m = fmaxf(m, __shfl_xor(m, off));
    float sum = 0.f;
#pragma unroll
    for (int i = 0; i < 16; ++i) {
        v[i] = __expf(v[i] - m);
        sum += v[i];
    }
#pragma unroll
    for (int off = 32; off; off >>= 1) sum += __shfl_xor(sum, off);
    const float inv = 1.0f / sum;
#pragma unroll
    for (int c = 0; c < 4; ++c) {
        ushort4 o;
        o.x = f2bf(v[c * 4 + 0] * inv);
        o.y = f2bf(v[c * 4 + 1] * inv);
        o.z = f2bf(v[c * 4 + 2] * inv);
        o.w = f2bf(v[c * 4 + 3] * inv);
        *(ushort4*)(rowp + c * 256 + lane * 4) = o;
    }
}

// ---------------------------------------------------------------- launch
extern "C" void kernel_launch(void* const* d_in, const int* in_sizes, int n_in,
                              void* d_out, int out_size, void* d_ws, size_t ws_size,
                              hipStream_t stream)
{
    (void)in_sizes; (void)n_in; (void)out_size; (void)ws_size;
    const float* x   = (const float*)d_in[0];
    const float* nsc = (const float*)d_in[1];
    const float* nbi = (const float*)d_in[2];
    const float* wq  = (const float*)d_in[3];
    const float* bq  = (const float*)d_in[4];
    const float* wk  = (const float*)d_in[5];
    const float* bk  = (const float*)d_in[6];
    const float* wv  = (const float*)d_in[7];
    const float* bv  = (const float*)d_in[8];
    const float* wp  = (const float*)d_in[9];
    const float* bp  = (const float*)d_in[10];
    float* out = (float*)d_out;

    char* ws = (char*)d_ws;
    u16* qb = (u16*)(ws);                        // 32 MB  [32768,512]  (q)
    u16* kb = (u16*)(ws + (32ull << 20));        // 32 MB  [32768,512]  (k)
    u16* vT = (u16*)(ws + (64ull << 20));        // 32 MB  [32,512,1024]
    u16* sb = (u16*)(ws + (96ull << 20));        // 64 MB  [32,1024,1024] (scores)
    u16* hn = (u16*)(ws + (160ull << 20));       // 32 MB  [32768,512]
    u16* ao = hn;                                 // reuse: hn dead after QKV
    u16* wT = (u16*)(ws + (192ull << 20));       // 2 MB   [4*512,512] stacked q,k,v,p
    float2* gnp = (float2*)sb;                   // 64 KB partials (dead before scores)
    float2* gns = (float2*)(ws + (97ull << 20)); // 8 KB stats

    transpose_weights<<<4096, 256, 0, stream>>>(wq, wk, wv, wp, wT);
    gn_partial<<<256, 256, 0, stream>>>(x, gnp);
    gn_stats<<<4, 256, 0, stream>>>(gnp, gns);
    gn_apply<<<16384, 256, 0, stream>>>(x, gns, nsc, nbi, hn);

    const dim3 blk(256);
    // fused QKV: N=1536 -> 12 n-blocks, M=32768 -> 256 m-strips.
    // Swizzled 1D grid: 8 XCDs * 32 strips/XCD * 12 n-blocks = 3072 blocks.
    gemm_bt<4, 12><<<3072, blk, 0, stream>>>(hn, wT, qb, vT, bq, bk, bv, nullptr,
                                             512, 512, 0, 0, 0, 1.f);

    const dim3 g2(8, 8, 32);                     // scores: N=1024, M=1024, 32 batches
    gemm_bt<0, 0><<<g2, blk, 0, stream>>>(qb, kb, sb, nullptr, nullptr, nullptr, nullptr, nullptr,
                                          512, 1024, 1024L * 512, 1024L * 512, 1024L * 1024,
                                          0.04419417382415922f);  // 512^-0.5
    softmax_kernel<<<8192, blk, 0, stream>>>(sb);

    const dim3 g3(4, 8, 32);                     // out: N=512, M=1024, 32 batches
    gemm_bt<0, 0><<<g3, blk, 0, stream>>>(sb, vT, ao, nullptr, nullptr, nullptr, nullptr, nullptr,
                                          1024, 512, 1024L * 1024, 512L * 1024, 1024L * 512,
                                          1.f);

    // proj: N=512 -> 4 n-blocks, M=32768 -> 256 m-strips; 8*64*4 = 2048... no:
    // 8 XCDs * 32 strips/XCD * 4 n-blocks = 1024 blocks (mper=32).
    gemm_bt<3, 4><<<1024, blk, 0, stream>>>(ao, wT + 3 * 262144, out, nullptr, bp, nullptr, nullptr, x,
                                            512, 512, 0, 0, 0, 1.f);
}